// Round 1
// baseline (1546.318 us; speedup 1.0000x reference)
//
#include <hip/hip_runtime.h>
#include <hip/hip_bf16.h>
#include <stdint.h>

#define B_ 8
#define S_ 2048
#define E_ 512
#define L_ 8929

typedef __attribute__((ext_vector_type(8))) short short8;
typedef __attribute__((ext_vector_type(4))) float floatx4;
typedef __hip_bfloat16 bf16;

__device__ __attribute__((always_inline)) inline void gload_lds16(const void* g, void* s) {
    __builtin_amdgcn_global_load_lds(
        (const __attribute__((address_space(1))) void*)g,
        (__attribute__((address_space(3))) void*)s,
        16, 0, 0);
}

// ---------- fp32 -> bf16 convert (vectorized) ----------
__global__ __launch_bounds__(256) void cvt_f32_bf16(const float* __restrict__ in,
                                                    bf16* __restrict__ out, long n4) {
    long i = (long)blockIdx.x * 256 + threadIdx.x;
    if (i >= n4) return;
    float4 v = ((const float4*)in)[i];
    struct alignas(8) B4 { bf16 h[4]; } o;
    o.h[0] = __float2bfloat16(v.x);
    o.h[1] = __float2bfloat16(v.y);
    o.h[2] = __float2bfloat16(v.z);
    o.h[3] = __float2bfloat16(v.w);
    ((B4*)out)[i] = o;
}

// ---------- x [B][S][E] fp32 -> xT [B][E][S] bf16 ----------
__global__ __launch_bounds__(256) void transpose_bf16(const float* __restrict__ x,
                                                      bf16* __restrict__ xT) {
    __shared__ bf16 t[32][33];
    int b = blockIdx.z, st = blockIdx.y * 32, et = blockIdx.x * 32;
    int tr = threadIdx.x >> 5, tc = threadIdx.x & 31;
    const float* xb = x + ((long)b * S_ + st) * E_ + et;
#pragma unroll
    for (int it = 0; it < 4; ++it) {
        int r = tr + it * 8;   // s-local
        t[r][tc] = __float2bfloat16(xb[(long)r * E_ + tc]);
    }
    __syncthreads();
    bf16* xTb = xT + ((long)b * E_ + et) * S_ + st;
#pragma unroll
    for (int it = 0; it < 4; ++it) {
        int r = tr + it * 8;   // e-local
        xTb[(long)r * S_ + tc] = t[tc][r];
    }
}

// ---------- GEMM1: scores[b][l][s] = sum_e U[l][e] * x[b][s][e] ----------
// A = U_bf16 [L][E], B = x_bf16[b] [S][E]  (NT form), C = scores fp32 [L][S]
__global__ __launch_bounds__(256) void gemm1(const bf16* __restrict__ A,
                                             const bf16* __restrict__ Bm,
                                             float* __restrict__ C) {
    const int tid = threadIdx.x;
    const int m0 = blockIdx.y * 128;
    const int n0 = blockIdx.x * 128;
    const int b  = blockIdx.z;
    const bf16* Bb = Bm + (long)b * S_ * E_;
    float* Cb = C + (long)b * L_ * S_;

    __shared__ alignas(16) bf16 As[128 * 32];
    __shared__ alignas(16) bf16 Bs[128 * 32];

    const int c0 = tid, c1 = tid + 256;           // 16B chunk ids (512 per tile)
    const int rA0 = min(m0 + (c0 >> 2), L_ - 1);
    const int rA1 = min(m0 + (c1 >> 2), L_ - 1);
    const int rB0 = n0 + (c0 >> 2);
    const int rB1 = n0 + (c1 >> 2);
    const bf16* pA0 = A + (long)rA0 * E_ + (c0 & 3) * 8;
    const bf16* pA1 = A + (long)rA1 * E_ + (c1 & 3) * 8;
    const bf16* pB0 = Bb + (long)rB0 * E_ + (c0 & 3) * 8;
    const bf16* pB1 = Bb + (long)rB1 * E_ + (c1 & 3) * 8;
    bf16* sA0 = As + c0 * 8; bf16* sA1 = As + c1 * 8;
    bf16* sB0 = Bs + c0 * 8; bf16* sB1 = Bs + c1 * 8;

    const int lane = tid & 63, lr = lane & 15, quad = lane >> 4;
    const int w = tid >> 6, wm = (w >> 1) * 64, wn = (w & 1) * 64;

    floatx4 acc[4][4] = {};

    for (int kb = 0; kb < E_; kb += 32) {
        gload_lds16(pA0, sA0);
        gload_lds16(pA1, sA1);
        gload_lds16(pB0, sB0);
        gload_lds16(pB1, sB1);
        pA0 += 32; pA1 += 32; pB0 += 32; pB1 += 32;
        __syncthreads();
        short8 af[4], bfv[4];
#pragma unroll
        for (int i = 0; i < 4; ++i)
            af[i] = *(const short8*)(As + (wm + i * 16 + lr) * 32 + quad * 8);
#pragma unroll
        for (int j = 0; j < 4; ++j)
            bfv[j] = *(const short8*)(Bs + (wn + j * 16 + lr) * 32 + quad * 8);
#pragma unroll
        for (int i = 0; i < 4; ++i)
#pragma unroll
            for (int j = 0; j < 4; ++j)
                acc[i][j] = __builtin_amdgcn_mfma_f32_16x16x32_bf16(af[i], bfv[j], acc[i][j], 0, 0, 0);
        __syncthreads();
    }
#pragma unroll
    for (int i = 0; i < 4; ++i) {
        int m = m0 + wm + i * 16 + quad * 4;
#pragma unroll
        for (int j = 0; j < 4; ++j) {
            int n = n0 + wn + j * 16 + lr;
#pragma unroll
            for (int r = 0; r < 4; ++r) {
                if (m + r < L_) Cb[(long)(m + r) * S_ + n] = acc[i][j][r];
            }
        }
    }
}

// ---------- per-row max & 1/sumexp ----------
__global__ __launch_bounds__(256) void row_stats_kernel(const float* __restrict__ sc,
                                                        float2* __restrict__ st) {
    const long row = blockIdx.x;   // b*L + l
    const int tid = threadIdx.x;
    const float* p = sc + row * S_;
    float4 v0 = ((const float4*)p)[tid];
    float4 v1 = ((const float4*)p)[tid + 256];
    float mx = fmaxf(fmaxf(fmaxf(v0.x, v0.y), fmaxf(v0.z, v0.w)),
                     fmaxf(fmaxf(v1.x, v1.y), fmaxf(v1.z, v1.w)));
#pragma unroll
    for (int off = 32; off >= 1; off >>= 1) mx = fmaxf(mx, __shfl_xor(mx, off));
    __shared__ float sm[4], ss[4];
    if ((tid & 63) == 0) sm[tid >> 6] = mx;
    __syncthreads();
    mx = fmaxf(fmaxf(sm[0], sm[1]), fmaxf(sm[2], sm[3]));
    float s = __expf(v0.x - mx) + __expf(v0.y - mx) + __expf(v0.z - mx) + __expf(v0.w - mx)
            + __expf(v1.x - mx) + __expf(v1.y - mx) + __expf(v1.z - mx) + __expf(v1.w - mx);
#pragma unroll
    for (int off = 32; off >= 1; off >>= 1) s += __shfl_xor(s, off);
    if ((tid & 63) == 0) ss[tid >> 6] = s;
    __syncthreads();
    if (tid == 0) st[row] = make_float2(mx, 1.0f / (ss[0] + ss[1] + ss[2] + ss[3]));
}

// ---------- GEMM2 (fused softmax): out[b][l][e] = sum_s alpha[b][l][s]*x[b][s][e] ----------
// BM=32, BN=512 (full E -> exclusive row ownership), BK=32.
// A-staging reads raw scores, writes normalized alpha fp32 in place, stages bf16 to LDS.
__global__ __launch_bounds__(256) void gemm2(float* __restrict__ Sc,       // scores/alpha [L][S] for batch b
                                             const float2* __restrict__ st,
                                             const bf16* __restrict__ Bt,  // xT bf16 [E][S]
                                             float* __restrict__ O) {      // out [L][E]
    const int tid = threadIdx.x;
    const int m0 = blockIdx.y * 32;
    const int b  = blockIdx.z;
    float* Scb = Sc + (long)b * L_ * S_;
    const bf16* Bb = Bt + (long)b * E_ * S_;
    float* Ob = O + (long)b * L_ * E_;
    const float2* stb = st + (long)b * L_;

    __shared__ alignas(16) bf16 As[32 * 32];
    __shared__ alignas(16) bf16 Bs[512 * 32];

    const int arow = tid >> 3;          // 0..31
    const int acol = (tid & 7) * 4;     // k offset within BK
    const bool own = (m0 + arow) < L_;
    const int gl = min(m0 + arow, L_ - 1);
    const float* pSc = Scb + (long)gl * S_ + acol;
    float* pAl = Scb + (long)gl * S_ + acol;
    const float2 s2 = stb[gl];
    const float mx = s2.x, inv = s2.y;

    const int brow = tid >> 2;          // 0..63
    const int bk = (tid & 3) * 8;
    const bf16* pB = Bb + (long)brow * S_ + bk;
    bf16* sB = Bs + tid * 8;

    const int lane = tid & 63, lr = lane & 15, quad = lane >> 4;
    const int wn = (tid >> 6) * 128;

    floatx4 acc[2][8] = {};

    for (int kb = 0; kb < S_; kb += 32) {
        // fused A staging: softmax-apply + alpha write + LDS stage
        float4 sc4 = *(const float4*)pSc;
        float4 al4;
        al4.x = __expf(sc4.x - mx) * inv;
        al4.y = __expf(sc4.y - mx) * inv;
        al4.z = __expf(sc4.z - mx) * inv;
        al4.w = __expf(sc4.w - mx) * inv;
        if (own) *(float4*)pAl = al4;   // exclusive owner -> race-free in-place
        struct alignas(8) B4 { bf16 h[4]; } a4;
        a4.h[0] = __float2bfloat16(al4.x);
        a4.h[1] = __float2bfloat16(al4.y);
        a4.h[2] = __float2bfloat16(al4.z);
        a4.h[3] = __float2bfloat16(al4.w);
        *(B4*)(As + arow * 32 + acol) = a4;
        // B staging: 8 x 16B chunks per thread, rows step 64
#pragma unroll
        for (int it = 0; it < 8; ++it)
            gload_lds16(pB + (long)it * 64 * S_ + kb, sB + it * 2048);
        pSc += 32; pAl += 32;
        __syncthreads();
        short8 af[2], bfv[8];
#pragma unroll
        for (int i = 0; i < 2; ++i)
            af[i] = *(const short8*)(As + (i * 16 + lr) * 32 + quad * 8);
#pragma unroll
        for (int j = 0; j < 8; ++j)
            bfv[j] = *(const short8*)(Bs + (wn + j * 16 + lr) * 32 + quad * 8);
#pragma unroll
        for (int i = 0; i < 2; ++i)
#pragma unroll
            for (int j = 0; j < 8; ++j)
                acc[i][j] = __builtin_amdgcn_mfma_f32_16x16x32_bf16(af[i], bfv[j], acc[i][j], 0, 0, 0);
        __syncthreads();
    }
#pragma unroll
    for (int i = 0; i < 2; ++i) {
        int m = m0 + i * 16 + quad * 4;
#pragma unroll
        for (int j = 0; j < 8; ++j) {
            int n = wn + j * 16 + lr;
#pragma unroll
            for (int r = 0; r < 4; ++r) {
                if (m + r < L_) Ob[(long)(m + r) * E_ + n] = acc[i][j][r];
            }
        }
    }
}

extern "C" void kernel_launch(void* const* d_in, const int* in_sizes, int n_in,
                              void* d_out, int out_size, void* d_ws, size_t ws_size,
                              hipStream_t stream) {
    (void)in_sizes; (void)n_in; (void)out_size; (void)ws_size;
    const float* x = (const float*)d_in[0];       // [B][S][E]
    const float* U = (const float*)d_in[1];       // [L][E]
    float* out   = (float*)d_out;                 // [B][L][E]
    float* alpha = out + (long)B_ * L_ * E_;      // [B][L][S] (scores, then alpha)

    char* ws = (char*)d_ws;
    bf16*   U_bf  = (bf16*)ws;                                        // L*E
    bf16*   x_bf  = (bf16*)(ws + 9143296);                            // B*S*E
    bf16*   xT_bf = (bf16*)(ws + 9143296 + 16777216);                 // B*E*S
    float2* stats = (float2*)(ws + 9143296 + 16777216 + 16777216);    // B*L

    long nU4 = (long)L_ * E_ / 4;
    cvt_f32_bf16<<<dim3((unsigned)((nU4 + 255) / 256)), dim3(256), 0, stream>>>(U, U_bf, nU4);
    long nX4 = (long)B_ * S_ * E_ / 4;
    cvt_f32_bf16<<<dim3((unsigned)((nX4 + 255) / 256)), dim3(256), 0, stream>>>(x, x_bf, nX4);
    transpose_bf16<<<dim3(E_ / 32, S_ / 32, B_), dim3(256), 0, stream>>>(x, xT_bf);
    gemm1<<<dim3(S_ / 128, (L_ + 127) / 128, B_), dim3(256), 0, stream>>>(U_bf, x_bf, alpha);
    row_stats_kernel<<<dim3(B_ * L_), dim3(256), 0, stream>>>(alpha, stats);
    gemm2<<<dim3(1, (L_ + 31) / 32, B_), dim3(256), 0, stream>>>(alpha, stats, xT_bf, out);
}